// Round 1
// baseline (1056.630 us; speedup 1.0000x reference)
//
#include <hip/hip_runtime.h>
#include <stdint.h>

// Problem constants
#define B_    32
#define T_    256
#define CD    100
#define BD    100
#define TD    20
#define LIN   200
#define HD    200
#define INDIM 420
#define G4    800   // 4*H

typedef __attribute__((ext_vector_type(8))) short bfrag8;   // 8 bf16 (4 VGPRs)
typedef __attribute__((ext_vector_type(4))) float f32x4v;   // MFMA accumulator

static __device__ __forceinline__ unsigned short f2bf(float f) {
  unsigned u = __float_as_uint(f);
  u = u + 0x7fffu + ((u >> 16) & 1u);   // RTNE
  return (unsigned short)(u >> 16);
}
static __device__ __forceinline__ float bf2f(unsigned short s) {
  return __uint_as_float(((unsigned)s) << 16);
}
static __device__ __forceinline__ float sigm(float x) {
  // 1/(1+e^-x) = rcp(1 + exp2(-x*log2e))
  return __builtin_amdgcn_rcpf(1.0f + __builtin_amdgcn_exp2f(x * -1.4426950408889634f));
}
static __device__ __forceinline__ float tanhx(float x) {
  // tanh(x) = 1 - 2/(e^{2x}+1)
  return 1.0f - 2.0f * __builtin_amdgcn_rcpf(1.0f + __builtin_amdgcn_exp2f(x * 2.8853900817779268f));
}

// split 8 f32 into hi/lo bf16 fragments (bf16x3 scheme)
static __device__ __forceinline__ void mk_hilo(float4 a, float4 b, bfrag8& hi, bfrag8& lo) {
  float q[8] = {a.x, a.y, a.z, a.w, b.x, b.y, b.z, b.w};
  #pragma unroll
  for (int j = 0; j < 8; ++j) {
    unsigned short h = f2bf(q[j]);
    hi[j] = (short)h;
    lo[j] = (short)f2bf(q[j] - bf2f(h));
  }
}
static __device__ __forceinline__ bfrag8 mk_hi(float4 a, float4 b) {
  bfrag8 r;
  float q[8] = {a.x, a.y, a.z, a.w, b.x, b.y, b.z, b.w};
  #pragma unroll
  for (int j = 0; j < 8; ++j) r[j] = (short)f2bf(q[j]);
  return r;
}

// ---------------------------------------------------------------------------
// Kernel W: pre-split fc_w and Wih_{l,r} into hi/lo bf16 in MFMA fragment layout
// frag layout: elem i = ((nt*KT + kt)*64 + lane)*8 + j ;
//   n = nt*16 + (lane&15), k = kt*32 + (lane>>4)*8 + j
// ---------------------------------------------------------------------------
__global__ void presplit_kernel(const float* __restrict__ fc_w,
                                const float* __restrict__ Wih_l,
                                const float* __restrict__ Wih_r,
                                unsigned short* __restrict__ fcw_hi,
                                unsigned short* __restrict__ fcw_lo,
                                unsigned short* __restrict__ wih_hi,
                                unsigned short* __restrict__ wih_lo) {
  int tid = blockIdx.x * blockDim.x + threadIdx.x;
  int stride = gridDim.x * blockDim.x;
  // fc_w: NT=13 (N=208 pad of 200), KT=14 (K=448 pad of 420)
  for (int i = tid; i < 13 * 14 * 512; i += stride) {
    int j = i & 7, l = (i >> 3) & 63, f = i >> 9;
    int kt = f % 14, nt = f / 14;
    int n = nt * 16 + (l & 15);
    int k = kt * 32 + ((l >> 4) << 3) + j;
    float v = (n < LIN && k < INDIM) ? fc_w[n * INDIM + k] : 0.0f;
    unsigned short h = f2bf(v);
    fcw_hi[i] = h;
    fcw_lo[i] = f2bf(v - bf2f(h));
  }
  // Wih: NT=50 (N=800), KT=7 (K=224 pad of 200), per direction
  for (int d = 0; d < 2; ++d) {
    const float* W = d ? Wih_r : Wih_l;
    unsigned short* oh = wih_hi + (size_t)d * 179200;
    unsigned short* ol = wih_lo + (size_t)d * 179200;
    for (int i = tid; i < 50 * 7 * 512; i += stride) {
      int j = i & 7, l = (i >> 3) & 63, f = i >> 9;
      int kt = f % 7, nt = f / 7;
      int n = nt * 16 + (l & 15);
      int k = kt * 32 + ((l >> 4) << 3) + j;
      float v = (k < LIN) ? W[n * LIN + k] : 0.0f;
      unsigned short h = f2bf(v);
      oh[i] = h;
      ol[i] = f2bf(v - bf2f(h));
    }
  }
}

// ---------------------------------------------------------------------------
// Kernel A: embedding gather + concat(420) + FC + tanh -> x [2*8192][200] f32
// One block per (dir, t): 32 rows (batch), full N=200. bf16x3 MFMA.
// ---------------------------------------------------------------------------
__global__ __launch_bounds__(256) void fc_kernel(
    const int* __restrict__ chars, const int* __restrict__ left_bichar,
    const int* __restrict__ right_bichar, const int* __restrict__ extchars,
    const int* __restrict__ extleft, const int* __restrict__ extright,
    const int* __restrict__ ctype,
    const float* __restrict__ E_char, const float* __restrict__ E_extchar,
    const float* __restrict__ E_bichar, const float* __restrict__ E_extbichar,
    const float* __restrict__ E_ctype, const float* __restrict__ fc_b,
    const unsigned short* __restrict__ fcw_hi, const unsigned short* __restrict__ fcw_lo,
    float* __restrict__ x) {
  __shared__ __align__(16) float feat[32 * 452];   // [32 rows][448 pad(+4)]
  int rb = blockIdx.x;            // 0..511 : dir*256 + t
  int dir = rb >> 8;
  int t = rb & 255;
  int tid = threadIdx.x;
  const int* bi  = dir ? right_bichar : left_bichar;
  const int* ebi = dir ? extright : extleft;

  // stage feat [32][452] (k >= 420 zero)
  for (int cc = tid; cc < 32 * 113; cc += 256) {
    int lr = cc / 113, kc = cc - lr * 113;
    int k = kc << 2;
    float4 v = make_float4(0.f, 0.f, 0.f, 0.f);
    if (k < INDIM) {
      int id; const float* tab; int kk; int wdt;
      if (k < 100)      { id = chars[lr * T_ + t];    tab = E_char;      kk = k;       wdt = 100; }
      else if (k < 200) { id = extchars[lr * T_ + t]; tab = E_extchar;   kk = k - 100; wdt = 100; }
      else if (k < 300) { id = bi[lr * T_ + t];       tab = E_bichar;    kk = k - 200; wdt = 100; }
      else if (k < 400) { id = ebi[lr * T_ + t];      tab = E_extbichar; kk = k - 300; wdt = 100; }
      else              { id = ctype[lr * T_ + t];    tab = E_ctype;     kk = k - 400; wdt = 20;  }
      v = *reinterpret_cast<const float4*>(tab + (size_t)id * wdt + kk);
    }
    *reinterpret_cast<float4*>(&feat[lr * 452 + k]) = v;
  }
  __syncthreads();

  int w = tid >> 6, l = tid & 63;
  int lrow = l & 15, lk8 = (l >> 4) << 3;
  f32x4v acc[8];
  #pragma unroll
  for (int i = 0; i < 8; ++i) acc[i] = (f32x4v){0.f, 0.f, 0.f, 0.f};

  for (int kt = 0; kt < 14; ++kt) {
    bfrag8 ah[2], al[2];
    #pragma unroll
    for (int mt = 0; mt < 2; ++mt) {
      const float* fp = &feat[(mt * 16 + lrow) * 452 + kt * 32 + lk8];
      float4 v0 = *reinterpret_cast<const float4*>(fp);
      float4 v1 = *reinterpret_cast<const float4*>(fp + 4);
      mk_hilo(v0, v1, ah[mt], al[mt]);
    }
    #pragma unroll
    for (int s = 0; s < 4; ++s) {
      int nt = w + (s << 2);
      if (nt < 13) {   // wave-uniform
        size_t fo = ((size_t)(nt * 14 + kt) * 64 + l) * 8;
        bfrag8 bh = *reinterpret_cast<const bfrag8*>(fcw_hi + fo);
        bfrag8 bl = *reinterpret_cast<const bfrag8*>(fcw_lo + fo);
        #pragma unroll
        for (int mt = 0; mt < 2; ++mt) {
          acc[s * 2 + mt] = __builtin_amdgcn_mfma_f32_16x16x32_bf16(ah[mt], bh, acc[s * 2 + mt], 0, 0, 0);
          acc[s * 2 + mt] = __builtin_amdgcn_mfma_f32_16x16x32_bf16(al[mt], bh, acc[s * 2 + mt], 0, 0, 0);
          acc[s * 2 + mt] = __builtin_amdgcn_mfma_f32_16x16x32_bf16(ah[mt], bl, acc[s * 2 + mt], 0, 0, 0);
        }
      }
    }
  }
  // epilogue: x = tanh(acc + fc_b)
  int r0 = rb * 32;   // = dir*8192 + t*32
  #pragma unroll
  for (int s = 0; s < 4; ++s) {
    int nt = w + (s << 2);
    if (nt < 13) {
      int n = nt * 16 + lrow;
      if (n < LIN) {
        float bias = fc_b[n];
        #pragma unroll
        for (int mt = 0; mt < 2; ++mt) {
          #pragma unroll
          for (int rr = 0; rr < 4; ++rr) {
            int row = mt * 16 + ((l >> 4) << 2) + rr;
            x[(size_t)(r0 + row) * LIN + n] = tanhx(acc[s * 2 + mt][rr] + bias);
          }
        }
      }
    }
  }
}

// ---------------------------------------------------------------------------
// Kernel B: pre = x @ Wih.T + b  -> [2][8192][800] f32. bf16x3 MFMA.
// 512 threads, tile M=128 (wave w -> 16 rows), N=160 per block.
// ---------------------------------------------------------------------------
__global__ __launch_bounds__(512) void xwih_kernel(
    const float* __restrict__ x, const unsigned short* __restrict__ wih_hi,
    const unsigned short* __restrict__ wih_lo, const float* __restrict__ b_l,
    const float* __restrict__ b_r, float* __restrict__ pre) {
  int bid = blockIdx.x;             // 640 = 2 * 64 * 5
  int dir = (bid >= 320) ? 1 : 0;
  int rem = bid - dir * 320;
  int rbm = rem / 5, nb = rem - rbm * 5;
  int m0 = rbm * 128, n0 = nb * 160;
  int tid = threadIdx.x, w = tid >> 6, l = tid & 63;
  int lrow = l & 15, lk8 = (l >> 4) << 3;
  const float* xd = x + (size_t)dir * 8192 * LIN;
  const unsigned short* wh = wih_hi + (size_t)dir * 179200;
  const unsigned short* wl = wih_lo + (size_t)dir * 179200;
  const float* bias = dir ? b_r : b_l;

  f32x4v acc[10];
  #pragma unroll
  for (int i = 0; i < 10; ++i) acc[i] = (f32x4v){0.f, 0.f, 0.f, 0.f};

  int row = m0 + w * 16 + lrow;
  for (int kt = 0; kt < 7; ++kt) {
    int kb = kt * 32 + lk8;
    bfrag8 ah = {0,0,0,0,0,0,0,0}, al = {0,0,0,0,0,0,0,0};
    if (kb <= 192) {   // in-bounds 8 floats (K=200)
      const float* fp = xd + (size_t)row * LIN + kb;
      float4 v0 = *reinterpret_cast<const float4*>(fp);
      float4 v1 = *reinterpret_cast<const float4*>(fp + 4);
      mk_hilo(v0, v1, ah, al);
    }
    #pragma unroll
    for (int nt = 0; nt < 10; ++nt) {
      int ntg = nb * 10 + nt;
      size_t fo = ((size_t)(ntg * 7 + kt) * 64 + l) * 8;
      bfrag8 bh = *reinterpret_cast<const bfrag8*>(wh + fo);
      bfrag8 bl = *reinterpret_cast<const bfrag8*>(wl + fo);
      acc[nt] = __builtin_amdgcn_mfma_f32_16x16x32_bf16(ah, bh, acc[nt], 0, 0, 0);
      acc[nt] = __builtin_amdgcn_mfma_f32_16x16x32_bf16(al, bh, acc[nt], 0, 0, 0);
      acc[nt] = __builtin_amdgcn_mfma_f32_16x16x32_bf16(ah, bl, acc[nt], 0, 0, 0);
    }
  }
  #pragma unroll
  for (int nt = 0; nt < 10; ++nt) {
    int n = n0 + nt * 16 + lrow;
    float bb = bias[n];
    #pragma unroll
    for (int rr = 0; rr < 4; ++rr) {
      int r2 = m0 + w * 16 + ((l >> 4) << 2) + rr;
      pre[(size_t)dir * 8192 * G4 + (size_t)r2 * G4 + n] = acc[nt][rr] + bb;
    }
  }
}

// ---------------------------------------------------------------------------
// Kernel R: the recurrence. 4 blocks = (dir, batch-half). Self-contained:
// each block runs 256 sequential steps of h[16,200] @ Whh.T -> gates[16,800],
// Whh register-resident as bf16 (48 tiles in VGPR, 2 in LDS), pre streamed
// into LDS via global_load_lds, LSTM elementwise in f32.
// ---------------------------------------------------------------------------
__global__ __launch_bounds__(512) void lstm_kernel(
    const float* __restrict__ pre, const float* __restrict__ Whh_l,
    const float* __restrict__ Whh_r, float* __restrict__ out) {
  __shared__ __align__(16) float gates[16 * 804];            // [16 b][800 n], stride 804
  __shared__ __align__(16) float preb[16 * 800];             // linear (global_load_lds dest)
  __shared__ __align__(16) unsigned int hfrag[7 * 64 * 4];   // a-frag layout, bf16
  __shared__ __align__(16) unsigned short whx[2 * 7 * 64 * 8]; // B-frags for nt=48,49

  int bi = blockIdx.x;
  int dir = bi >> 1, half = bi & 1;
  const float* Whh = dir ? Whh_r : Whh_l;
  int tid = threadIdx.x, w = tid >> 6, l = tid & 63;
  int lrow = l & 15, lk8 = (l >> 4) << 3;

  // --- stage Whh: register-resident B-frags, nt = w + 8i (i<6) ---
  bfrag8 Breg[6][7];
  #pragma unroll
  for (int i = 0; i < 6; ++i) {
    int nt = w + (i << 3);
    #pragma unroll
    for (int kt = 0; kt < 7; ++kt) {
      int n = nt * 16 + lrow;
      int kb = kt * 32 + lk8;
      bfrag8 bb = {0,0,0,0,0,0,0,0};
      if (kb <= 192) {
        const float* fp = Whh + (size_t)n * HD + kb;
        float4 v0 = *reinterpret_cast<const float4*>(fp);
        float4 v1 = *reinterpret_cast<const float4*>(fp + 4);
        bb = mk_hi(v0, v1);
      }
      Breg[i][kt] = bb;
    }
  }
  // --- stage overflow tiles nt=48,49 into LDS ---
  for (int e = tid; e < 2 * 7 * 64; e += 512) {
    int l2 = e & 63, f = e >> 6;          // f = tile*7 + kt
    int kt = f % 7, tile = f / 7;
    int n = (48 + tile) * 16 + (l2 & 15);
    int kb = kt * 32 + ((l2 >> 4) << 3);
    bfrag8 bb = {0,0,0,0,0,0,0,0};
    if (kb <= 192) {
      const float* fp = Whh + (size_t)n * HD + kb;
      float4 v0 = *reinterpret_cast<const float4*>(fp);
      float4 v1 = *reinterpret_cast<const float4*>(fp + 4);
      bb = mk_hi(v0, v1);
    }
    *reinterpret_cast<bfrag8*>(&whx[(size_t)(f * 64 + l2) * 8]) = bb;
  }
  // zero h fragments (h0 = 0); kt=6 upper lanes stay zero forever (K pad)
  for (int e = tid; e < 7 * 64 * 4; e += 512) hfrag[e] = 0;
  float c[7];
  #pragma unroll
  for (int r = 0; r < 7; ++r) c[r] = 0.0f;
  __syncthreads();

  const char* preB = (const char*)(pre + (size_t)dir * 8192 * G4 + (size_t)half * 16 * G4);
  char* dstb = (char*)preb;

  for (int it = 0; it < 256; ++it) {
    int t = dir ? (255 - it) : it;
    // --- issue async pre-gate load for THIS step (hidden under MFMA phase) ---
    {
      const char* src = preB + (size_t)t * 32 * G4 * 4;   // 16 rows x 800 f32 contiguous
      #pragma unroll
      for (int i2 = 0; i2 < 7; ++i2) {
        int cchunk = w + (i2 << 3);          // wave-uniform chunk id
        if (cchunk < 50) {
          __builtin_amdgcn_global_load_lds(
              (const __attribute__((address_space(1))) void*)(src + cchunk * 1024 + l * 16),
              (__attribute__((address_space(3))) void*)(dstb + cchunk * 1024),
              16, 0, 0);
        }
      }
    }
    // --- MFMA phase: gates_slice = h @ Whh.T ---
    f32x4v acc[7];
    #pragma unroll
    for (int i = 0; i < 7; ++i) acc[i] = (f32x4v){0.f, 0.f, 0.f, 0.f};
    #pragma unroll
    for (int kt = 0; kt < 7; ++kt) {
      bfrag8 a = *reinterpret_cast<const bfrag8*>(&hfrag[(kt * 64 + l) * 4]);
      #pragma unroll
      for (int i = 0; i < 6; ++i)
        acc[i] = __builtin_amdgcn_mfma_f32_16x16x32_bf16(a, Breg[i][kt], acc[i], 0, 0, 0);
      if (w < 2) {
        bfrag8 bx = *reinterpret_cast<const bfrag8*>(&whx[(size_t)((w * 7 + kt) * 64 + l) * 8]);
        acc[6] = __builtin_amdgcn_mfma_f32_16x16x32_bf16(a, bx, acc[6], 0, 0, 0);
      }
    }
    // write gates to LDS: D row=(l>>4)*4+rr (batch), col=lane&15
    int grow = (l >> 4) << 2;
    #pragma unroll
    for (int i = 0; i < 6; ++i) {
      int n = (w + (i << 3)) * 16 + lrow;
      #pragma unroll
      for (int rr = 0; rr < 4; ++rr)
        gates[(grow + rr) * 804 + n] = acc[i][rr];
    }
    if (w < 2) {
      int n = (48 + w) * 16 + lrow;
      #pragma unroll
      for (int rr = 0; rr < 4; ++rr)
        gates[(grow + rr) * 804 + n] = acc[6][rr];
    }
    asm volatile("s_waitcnt vmcnt(0)" ::: "memory");   // pre loads landed in LDS
    __syncthreads();

    // --- elementwise LSTM cell: 3200 items = 16 b x 200 hcol ---
    #pragma unroll
    for (int r = 0; r < 7; ++r) {
      if (r < 6 || tid < 128) {    // r==6 guard is wave-uniform (waves 0,1)
        int item = tid + (r << 9);
        int b = item / 200;
        int hcol = item - b * 200;
        int pb = b * 800 + hcol;
        int gb = b * 804 + hcol;
        float ig = preb[pb]       + gates[gb];
        float fg = preb[pb + 200] + gates[gb + 200];
        float gg = preb[pb + 400] + gates[gb + 400];
        float og = preb[pb + 600] + gates[gb + 600];
        float cv = sigm(fg) * c[r] + sigm(ig) * tanhx(gg);
        c[r] = cv;
        float h = sigm(og) * tanhx(cv);
        out[(size_t)((half * 16 + b) * 256 + t) * 400 + dir * 200 + hcol] = h;
        // scatter h into a-frag layout for next step
        int hp = ((hcol >> 5) * 64 + b + (((hcol & 31) >> 3) << 4)) * 8 + (hcol & 7);
        reinterpret_cast<unsigned short*>(hfrag)[hp] = f2bf(h);
      }
    }
    __syncthreads();
  }
}

// ---------------------------------------------------------------------------
extern "C" void kernel_launch(void* const* d_in, const int* in_sizes, int n_in,
                              void* d_out, int out_size, void* d_ws, size_t ws_size,
                              hipStream_t stream) {
  (void)in_sizes; (void)n_in; (void)out_size; (void)ws_size;
  const int* chars        = (const int*)d_in[0];
  const int* left_bichar  = (const int*)d_in[1];
  const int* right_bichar = (const int*)d_in[2];
  const int* extchars     = (const int*)d_in[3];
  const int* extleft      = (const int*)d_in[4];
  const int* extright     = (const int*)d_in[5];
  const int* ctype        = (const int*)d_in[6];
  const float* E_char      = (const float*)d_in[7];
  const float* E_extchar   = (const float*)d_in[8];
  const float* E_bichar    = (const float*)d_in[9];
  const float* E_extbichar = (const float*)d_in[10];
  const float* E_ctype     = (const float*)d_in[11];
  const float* fc_w  = (const float*)d_in[12];
  const float* fc_b  = (const float*)d_in[13];
  const float* Wih_l = (const float*)d_in[14];
  const float* Whh_l = (const float*)d_in[15];
  const float* b_l   = (const float*)d_in[16];
  const float* Wih_r = (const float*)d_in[17];
  const float* Whh_r = (const float*)d_in[18];
  const float* b_r   = (const float*)d_in[19];
  float* out = (float*)d_out;
  char* ws = (char*)d_ws;

  // workspace layout (bytes)
  float* x   = (float*)(ws);                        // 2*8192*200*4 = 13,107,200
  float* pre = (float*)(ws + 13107200);             // 2*8192*800*4 = 52,428,800
  unsigned short* fcw_hi = (unsigned short*)(ws + 65536000);   // 93,184*2 = 186,368
  unsigned short* fcw_lo = (unsigned short*)(ws + 65722368);   // 186,368
  unsigned short* wih_hi = (unsigned short*)(ws + 65908736);   // 2*179,200*2 = 716,800
  unsigned short* wih_lo = (unsigned short*)(ws + 66625536);   // 716,800 -> end 67,342,336

  presplit_kernel<<<256, 256, 0, stream>>>(fc_w, Wih_l, Wih_r, fcw_hi, fcw_lo, wih_hi, wih_lo);
  fc_kernel<<<512, 256, 0, stream>>>(chars, left_bichar, right_bichar, extchars,
                                     extleft, extright, ctype, E_char, E_extchar,
                                     E_bichar, E_extbichar, E_ctype, fc_b,
                                     fcw_hi, fcw_lo, x);
  xwih_kernel<<<640, 512, 0, stream>>>(x, wih_hi, wih_lo, b_l, b_r, pre);
  lstm_kernel<<<4, 512, 0, stream>>>(pre, Whh_l, Whh_r, out);
}

// Round 2
// 894.547 us; speedup vs baseline: 1.1812x; 1.1812x over previous
//
#include <hip/hip_runtime.h>
#include <stdint.h>

// Problem constants
#define B_    32
#define T_    256
#define CD    100
#define BD    100
#define TD    20
#define LIN   200
#define HD    200
#define INDIM 420
#define G4    800   // 4*H

typedef __attribute__((ext_vector_type(8))) short bfrag8;   // 8 bf16 (4 VGPRs)
typedef __attribute__((ext_vector_type(4))) float f32x4v;   // MFMA accumulator

static __device__ __forceinline__ unsigned short f2bf(float f) {
  unsigned u = __float_as_uint(f);
  u = u + 0x7fffu + ((u >> 16) & 1u);   // RTNE
  return (unsigned short)(u >> 16);
}
static __device__ __forceinline__ float bf2f(unsigned short s) {
  return __uint_as_float(((unsigned)s) << 16);
}
static __device__ __forceinline__ float sigm(float x) {
  return __builtin_amdgcn_rcpf(1.0f + __builtin_amdgcn_exp2f(x * -1.4426950408889634f));
}
static __device__ __forceinline__ float tanhx(float x) {
  return 1.0f - 2.0f * __builtin_amdgcn_rcpf(1.0f + __builtin_amdgcn_exp2f(x * 2.8853900817779268f));
}

static __device__ __forceinline__ void mk_hilo(float4 a, float4 b, bfrag8& hi, bfrag8& lo) {
  float q[8] = {a.x, a.y, a.z, a.w, b.x, b.y, b.z, b.w};
  #pragma unroll
  for (int j = 0; j < 8; ++j) {
    unsigned short h = f2bf(q[j]);
    hi[j] = (short)h;
    lo[j] = (short)f2bf(q[j] - bf2f(h));
  }
}
static __device__ __forceinline__ bfrag8 mk_hi(float4 a, float4 b) {
  bfrag8 r;
  float q[8] = {a.x, a.y, a.z, a.w, b.x, b.y, b.z, b.w};
  #pragma unroll
  for (int j = 0; j < 8; ++j) r[j] = (short)f2bf(q[j]);
  return r;
}

// ---------------------------------------------------------------------------
// Kernel W: pre-split fc_w and Wih_{l,r} into hi/lo bf16 in MFMA fragment layout
// frag layout: elem i = ((nt*KT + kt)*64 + lane)*8 + j ;
//   n = nt*16 + (lane&15), k = kt*32 + (lane>>4)*8 + j
// Wih rows are PERMUTED: frag col n' maps to original row (n'&3)*200 + (n'>>2)
// (i.e. n' = 4*hcol + gate, gate order i,f,g,o) so that gates arrive
// gate-adjacent for the LSTM cell.
// ---------------------------------------------------------------------------
__global__ void presplit_kernel(const float* __restrict__ fc_w,
                                const float* __restrict__ Wih_l,
                                const float* __restrict__ Wih_r,
                                unsigned short* __restrict__ fcw_hi,
                                unsigned short* __restrict__ fcw_lo,
                                unsigned short* __restrict__ wih_hi,
                                unsigned short* __restrict__ wih_lo) {
  int tid = blockIdx.x * blockDim.x + threadIdx.x;
  int stride = gridDim.x * blockDim.x;
  // fc_w: NT=13 (N=208 pad of 200), KT=14 (K=448 pad of 420) — unpermuted
  for (int i = tid; i < 13 * 14 * 512; i += stride) {
    int j = i & 7, l = (i >> 3) & 63, f = i >> 9;
    int kt = f % 14, nt = f / 14;
    int n = nt * 16 + (l & 15);
    int k = kt * 32 + ((l >> 4) << 3) + j;
    float v = (n < LIN && k < INDIM) ? fc_w[n * INDIM + k] : 0.0f;
    unsigned short h = f2bf(v);
    fcw_hi[i] = h;
    fcw_lo[i] = f2bf(v - bf2f(h));
  }
  // Wih: NT=50 (N=800), KT=7 (K=224 pad of 200), per direction, PERMUTED rows
  for (int d = 0; d < 2; ++d) {
    const float* W = d ? Wih_r : Wih_l;
    unsigned short* oh = wih_hi + (size_t)d * 179200;
    unsigned short* ol = wih_lo + (size_t)d * 179200;
    for (int i = tid; i < 50 * 7 * 512; i += stride) {
      int j = i & 7, l = (i >> 3) & 63, f = i >> 9;
      int kt = f % 7, nt = f / 7;
      int np = nt * 16 + (l & 15);                 // permuted col n'
      int no = (np & 3) * 200 + (np >> 2);         // original Wih row
      int k = kt * 32 + ((l >> 4) << 3) + j;
      float v = (k < LIN) ? W[no * LIN + k] : 0.0f;
      unsigned short h = f2bf(v);
      oh[i] = h;
      ol[i] = f2bf(v - bf2f(h));
    }
  }
}

// ---------------------------------------------------------------------------
// Kernel A: embedding gather + concat(420) + FC + tanh -> x [2*8192][200] f32
// ---------------------------------------------------------------------------
__global__ __launch_bounds__(256) void fc_kernel(
    const int* __restrict__ chars, const int* __restrict__ left_bichar,
    const int* __restrict__ right_bichar, const int* __restrict__ extchars,
    const int* __restrict__ extleft, const int* __restrict__ extright,
    const int* __restrict__ ctype,
    const float* __restrict__ E_char, const float* __restrict__ E_extchar,
    const float* __restrict__ E_bichar, const float* __restrict__ E_extbichar,
    const float* __restrict__ E_ctype, const float* __restrict__ fc_b,
    const unsigned short* __restrict__ fcw_hi, const unsigned short* __restrict__ fcw_lo,
    float* __restrict__ x) {
  __shared__ __align__(16) float feat[32 * 452];
  int rb = blockIdx.x;            // dir*256 + t
  int dir = rb >> 8;
  int t = rb & 255;
  int tid = threadIdx.x;
  const int* bi  = dir ? right_bichar : left_bichar;
  const int* ebi = dir ? extright : extleft;

  for (int cc = tid; cc < 32 * 113; cc += 256) {
    int lr = cc / 113, kc = cc - lr * 113;
    int k = kc << 2;
    float4 v = make_float4(0.f, 0.f, 0.f, 0.f);
    if (k < INDIM) {
      int id; const float* tab; int kk; int wdt;
      if (k < 100)      { id = chars[lr * T_ + t];    tab = E_char;      kk = k;       wdt = 100; }
      else if (k < 200) { id = extchars[lr * T_ + t]; tab = E_extchar;   kk = k - 100; wdt = 100; }
      else if (k < 300) { id = bi[lr * T_ + t];       tab = E_bichar;    kk = k - 200; wdt = 100; }
      else if (k < 400) { id = ebi[lr * T_ + t];      tab = E_extbichar; kk = k - 300; wdt = 100; }
      else              { id = ctype[lr * T_ + t];    tab = E_ctype;     kk = k - 400; wdt = 20;  }
      v = *reinterpret_cast<const float4*>(tab + (size_t)id * wdt + kk);
    }
    *reinterpret_cast<float4*>(&feat[lr * 452 + k]) = v;
  }
  __syncthreads();

  int w = tid >> 6, l = tid & 63;
  int lrow = l & 15, lk8 = (l >> 4) << 3;
  f32x4v acc[8];
  #pragma unroll
  for (int i = 0; i < 8; ++i) acc[i] = (f32x4v){0.f, 0.f, 0.f, 0.f};

  for (int kt = 0; kt < 14; ++kt) {
    bfrag8 ah[2], al[2];
    #pragma unroll
    for (int mt = 0; mt < 2; ++mt) {
      const float* fp = &feat[(mt * 16 + lrow) * 452 + kt * 32 + lk8];
      float4 v0 = *reinterpret_cast<const float4*>(fp);
      float4 v1 = *reinterpret_cast<const float4*>(fp + 4);
      mk_hilo(v0, v1, ah[mt], al[mt]);
    }
    #pragma unroll
    for (int s = 0; s < 4; ++s) {
      int nt = w + (s << 2);
      if (nt < 13) {
        size_t fo = ((size_t)(nt * 14 + kt) * 64 + l) * 8;
        bfrag8 bh = *reinterpret_cast<const bfrag8*>(fcw_hi + fo);
        bfrag8 bl = *reinterpret_cast<const bfrag8*>(fcw_lo + fo);
        #pragma unroll
        for (int mt = 0; mt < 2; ++mt) {
          acc[s * 2 + mt] = __builtin_amdgcn_mfma_f32_16x16x32_bf16(ah[mt], bh, acc[s * 2 + mt], 0, 0, 0);
          acc[s * 2 + mt] = __builtin_amdgcn_mfma_f32_16x16x32_bf16(al[mt], bh, acc[s * 2 + mt], 0, 0, 0);
          acc[s * 2 + mt] = __builtin_amdgcn_mfma_f32_16x16x32_bf16(ah[mt], bl, acc[s * 2 + mt], 0, 0, 0);
        }
      }
    }
  }
  int r0 = rb * 32;
  #pragma unroll
  for (int s = 0; s < 4; ++s) {
    int nt = w + (s << 2);
    if (nt < 13) {
      int n = nt * 16 + lrow;
      if (n < LIN) {
        float bias = fc_b[n];
        #pragma unroll
        for (int mt = 0; mt < 2; ++mt) {
          #pragma unroll
          for (int rr = 0; rr < 4; ++rr) {
            int row = mt * 16 + ((l >> 4) << 2) + rr;
            x[(size_t)(r0 + row) * LIN + n] = tanhx(acc[s * 2 + mt][rr] + bias);
          }
        }
      }
    }
  }
}

// ---------------------------------------------------------------------------
// Kernel B: pre = x @ Wih'.T + b'  -> [2][8192][800] f32 (PERMUTED cols n').
// ---------------------------------------------------------------------------
__global__ __launch_bounds__(512) void xwih_kernel(
    const float* __restrict__ x, const unsigned short* __restrict__ wih_hi,
    const unsigned short* __restrict__ wih_lo, const float* __restrict__ b_l,
    const float* __restrict__ b_r, float* __restrict__ pre) {
  int bid = blockIdx.x;             // 640 = 2 * 64 * 5
  int dir = (bid >= 320) ? 1 : 0;
  int rem = bid - dir * 320;
  int rbm = rem / 5, nb = rem - rbm * 5;
  int m0 = rbm * 128, n0 = nb * 160;
  int tid = threadIdx.x, w = tid >> 6, l = tid & 63;
  int lrow = l & 15, lk8 = (l >> 4) << 3;
  const float* xd = x + (size_t)dir * 8192 * LIN;
  const unsigned short* wh = wih_hi + (size_t)dir * 179200;
  const unsigned short* wl = wih_lo + (size_t)dir * 179200;
  const float* bias = dir ? b_r : b_l;

  f32x4v acc[10];
  #pragma unroll
  for (int i = 0; i < 10; ++i) acc[i] = (f32x4v){0.f, 0.f, 0.f, 0.f};

  int row = m0 + w * 16 + lrow;
  for (int kt = 0; kt < 7; ++kt) {
    int kb = kt * 32 + lk8;
    bfrag8 ah = {0,0,0,0,0,0,0,0}, al = {0,0,0,0,0,0,0,0};
    if (kb <= 192) {
      const float* fp = xd + (size_t)row * LIN + kb;
      float4 v0 = *reinterpret_cast<const float4*>(fp);
      float4 v1 = *reinterpret_cast<const float4*>(fp + 4);
      mk_hilo(v0, v1, ah, al);
    }
    #pragma unroll
    for (int nt = 0; nt < 10; ++nt) {
      int ntg = nb * 10 + nt;
      size_t fo = ((size_t)(ntg * 7 + kt) * 64 + l) * 8;
      bfrag8 bh = *reinterpret_cast<const bfrag8*>(wh + fo);
      bfrag8 bl = *reinterpret_cast<const bfrag8*>(wl + fo);
      acc[nt] = __builtin_amdgcn_mfma_f32_16x16x32_bf16(ah, bh, acc[nt], 0, 0, 0);
      acc[nt] = __builtin_amdgcn_mfma_f32_16x16x32_bf16(al, bh, acc[nt], 0, 0, 0);
      acc[nt] = __builtin_amdgcn_mfma_f32_16x16x32_bf16(ah, bl, acc[nt], 0, 0, 0);
    }
  }
  #pragma unroll
  for (int nt = 0; nt < 10; ++nt) {
    int n = n0 + nt * 16 + lrow;                    // permuted col n'
    float bb = bias[(n & 3) * 200 + (n >> 2)];      // original bias row
    #pragma unroll
    for (int rr = 0; rr < 4; ++rr) {
      int r2 = m0 + w * 16 + ((l >> 4) << 2) + rr;
      pre[(size_t)dir * 8192 * G4 + (size_t)r2 * G4 + n] = acc[nt][rr] + bb;
    }
  }
}

// ---------------------------------------------------------------------------
// Kernel R: recurrence, 4 blocks = (dir, batch-half), 512 thr, M=16.
// gates^T = Whh' @ h^T: A = Whh' frag (rows n' = 4*hcol+gate), B = h frag.
// D: lane l, reg rr -> gate rr of cell (b = l&15, hcol = 4*tau + (l>>4)).
// -> cell is fully in-register (no gates LDS, ONE barrier/step, lgkm-only).
// Whh': 5 tiles/wave in VGPR + tiles 40..49 in LDS. pre read as float4/cell
// from global, prefetched one step ahead into the same registers.
// ---------------------------------------------------------------------------
__global__ __launch_bounds__(512, 2) void lstm_kernel(
    const float* __restrict__ pre, const float* __restrict__ Whh_l,
    const float* __restrict__ Whh_r, float* __restrict__ out) {
  __shared__ __align__(16) unsigned short hbufA[3584];   // [kt:7][lane:64][j:8] bf16
  __shared__ __align__(16) unsigned short hbufB[3584];
  __shared__ __align__(16) unsigned short whx[35840];    // tiles 40..49 A-frags

  int bi = blockIdx.x;
  int dir = bi >> 1, half = bi & 1;
  const float* Whh = dir ? Whh_r : Whh_l;
  int tid = threadIdx.x, w = tid >> 6, l = tid & 63;
  int lrow = l & 15, lk8 = (l >> 4) << 3;

  // --- register-resident Whh' A-frags: tiles tau = w + 8i, i<5 ---
  bfrag8 Breg[5][7];
  #pragma unroll
  for (int i = 0; i < 5; ++i) {
    int np = (w + 8 * i) * 16 + lrow;
    int no = (np & 3) * 200 + (np >> 2);
    #pragma unroll
    for (int kt = 0; kt < 7; ++kt) {
      int kb = kt * 32 + lk8;
      bfrag8 bb = {0,0,0,0,0,0,0,0};
      if (kb <= 192) {
        const float* fp = Whh + (size_t)no * HD + kb;
        bb = mk_hi(*reinterpret_cast<const float4*>(fp),
                   *reinterpret_cast<const float4*>(fp + 4));
      }
      Breg[i][kt] = bb;
    }
  }
  // --- LDS tiles 40..49 ---
  for (int e = tid; e < 4480; e += 512) {
    int l2 = e & 63, f = e >> 6;          // f = tile*7 + kt
    int kt = f % 7, tile = f / 7;
    int np = (40 + tile) * 16 + (l2 & 15);
    int no = (np & 3) * 200 + (np >> 2);
    int kb = kt * 32 + ((l2 >> 4) << 3);
    bfrag8 bb = {0,0,0,0,0,0,0,0};
    if (kb <= 192) {
      const float* fp = Whh + (size_t)no * HD + kb;
      bb = mk_hi(*reinterpret_cast<const float4*>(fp),
                 *reinterpret_cast<const float4*>(fp + 4));
    }
    *reinterpret_cast<bfrag8*>(&whx[(size_t)e * 8]) = bb;
  }
  // zero h buffers (h0 = 0; K-pad positions stay zero forever)
  for (int e = tid; e < 896; e += 512) {
    reinterpret_cast<uint64_t*>(hbufA)[e] = 0;
    reinterpret_cast<uint64_t*>(hbufB)[e] = 0;
  }
  float c[7];
  #pragma unroll
  for (int i = 0; i < 7; ++i) c[i] = 0.f;

  // hfrag write slot for this lane (kt handled by +i*512)
  int hbase = 4 * w + (l >> 4);                       // hcol mod 32, < 32
  int hw = (lrow + 16 * ((hbase >> 3) & 3)) * 8 + (hbase & 7);

  const float* psrc = pre + (size_t)dir * 8192 * G4
                    + (size_t)(dir ? 255 : 0) * 32 * G4
                    + (half * 16 + lrow) * G4 + ((l >> 4) << 2) + 16 * w;
  float* outp = out + (size_t)((half * 16 + lrow) * 256 + (dir ? 255 : 0)) * 400
              + dir * 200 + (l >> 4) + 4 * w;
  const int pstep = dir ? -(32 * G4) : (32 * G4);
  const int ostep = dir ? -400 : 400;

  __syncthreads();

  // prefetch pre for first step
  float4 p[7];
  #pragma unroll
  for (int i = 0; i < 7; ++i)
    if (i < 6 || w < 2) p[i] = *reinterpret_cast<const float4*>(psrc + 128 * i);

  auto STEP = [&](const unsigned short* rbuf, unsigned short* wbuf) {
    f32x4v acc[7];
    #pragma unroll
    for (int i = 0; i < 7; ++i) acc[i] = (f32x4v){0.f, 0.f, 0.f, 0.f};
    #pragma unroll
    for (int kt = 0; kt < 7; ++kt) {
      bfrag8 hf = *reinterpret_cast<const bfrag8*>(&rbuf[kt * 512 + l * 8]);
      #pragma unroll
      for (int i = 0; i < 5; ++i)
        acc[i] = __builtin_amdgcn_mfma_f32_16x16x32_bf16(Breg[i][kt], hf, acc[i], 0, 0, 0);
      bfrag8 b5 = *reinterpret_cast<const bfrag8*>(&whx[(w * 7 + kt) * 512 + l * 8]);
      acc[5] = __builtin_amdgcn_mfma_f32_16x16x32_bf16(b5, hf, acc[5], 0, 0, 0);
      if (w < 2) {
        bfrag8 b6 = *reinterpret_cast<const bfrag8*>(&whx[((8 + w) * 7 + kt) * 512 + l * 8]);
        acc[6] = __builtin_amdgcn_mfma_f32_16x16x32_bf16(b6, hf, acc[6], 0, 0, 0);
      }
    }
    // in-register LSTM cell: lane owns (b = l&15, hcol = 4*(w+8i) + (l>>4))
    #pragma unroll
    for (int i = 0; i < 7; ++i) {
      if (i < 6 || w < 2) {
        float ig = acc[i][0] + p[i].x;
        float fg = acc[i][1] + p[i].y;
        float gg = acc[i][2] + p[i].z;
        float og = acc[i][3] + p[i].w;
        float cv = sigm(fg) * c[i] + sigm(ig) * tanhx(gg);
        c[i] = cv;
        float h = sigm(og) * tanhx(cv);
        outp[32 * i] = h;
        wbuf[hw + i * 512] = f2bf(h);
      }
    }
    // advance + prefetch pre for NEXT step (same regs; lands after barrier)
    psrc += pstep; outp += ostep;
    #pragma unroll
    for (int i = 0; i < 7; ++i)
      if (i < 6 || w < 2) p[i] = *reinterpret_cast<const float4*>(psrc + 128 * i);
    asm volatile("s_waitcnt lgkmcnt(0)\n\ts_barrier" ::: "memory");
  };

  for (int it = 0; it < 128; ++it) {
    STEP(hbufA, hbufB);
    STEP(hbufB, hbufA);
  }
}

// ---------------------------------------------------------------------------
extern "C" void kernel_launch(void* const* d_in, const int* in_sizes, int n_in,
                              void* d_out, int out_size, void* d_ws, size_t ws_size,
                              hipStream_t stream) {
  (void)in_sizes; (void)n_in; (void)out_size; (void)ws_size;
  const int* chars        = (const int*)d_in[0];
  const int* left_bichar  = (const int*)d_in[1];
  const int* right_bichar = (const int*)d_in[2];
  const int* extchars     = (const int*)d_in[3];
  const int* extleft      = (const int*)d_in[4];
  const int* extright     = (const int*)d_in[5];
  const int* ctype        = (const int*)d_in[6];
  const float* E_char      = (const float*)d_in[7];
  const float* E_extchar   = (const float*)d_in[8];
  const float* E_bichar    = (const float*)d_in[9];
  const float* E_extbichar = (const float*)d_in[10];
  const float* E_ctype     = (const float*)d_in[11];
  const float* fc_w  = (const float*)d_in[12];
  const float* fc_b  = (const float*)d_in[13];
  const float* Wih_l = (const float*)d_in[14];
  const float* Whh_l = (const float*)d_in[15];
  const float* b_l   = (const float*)d_in[16];
  const float* Wih_r = (const float*)d_in[17];
  const float* Whh_r = (const float*)d_in[18];
  const float* b_r   = (const float*)d_in[19];
  float* out = (float*)d_out;
  char* ws = (char*)d_ws;

  float* x   = (float*)(ws);                        // 13,107,200 B
  float* pre = (float*)(ws + 13107200);             // 52,428,800 B
  unsigned short* fcw_hi = (unsigned short*)(ws + 65536000);   // 186,368
  unsigned short* fcw_lo = (unsigned short*)(ws + 65722368);   // 186,368
  unsigned short* wih_hi = (unsigned short*)(ws + 65908736);   // 716,800
  unsigned short* wih_lo = (unsigned short*)(ws + 66625536);   // 716,800

  presplit_kernel<<<256, 256, 0, stream>>>(fc_w, Wih_l, Wih_r, fcw_hi, fcw_lo, wih_hi, wih_lo);
  fc_kernel<<<512, 256, 0, stream>>>(chars, left_bichar, right_bichar, extchars,
                                     extleft, extright, ctype, E_char, E_extchar,
                                     E_bichar, E_extbichar, E_ctype, fc_b,
                                     fcw_hi, fcw_lo, x);
  xwih_kernel<<<640, 512, 0, stream>>>(x, wih_hi, wih_lo, b_l, b_r, pre);
  lstm_kernel<<<4, 512, 0, stream>>>(pre, Whh_l, Whh_r, out);
}